// Round 11
// baseline (496.244 us; speedup 1.0000x reference)
//
#include <hip/hip_runtime.h>
#include <stdint.h>

// Sizes (fixed by the problem)
#define N_PATCH 8192
#define DIM     1024
#define HID     512
#define NHEAD   16

using short8 = __attribute__((ext_vector_type(8))) short;
using f32x4  = __attribute__((ext_vector_type(4))) float;

__device__ __forceinline__ unsigned short f2bf(float f) {
  unsigned u = __float_as_uint(f);
  u = u + 0x7fffu + ((u >> 16) & 1u);   // round-to-nearest-even
  return (unsigned short)(u >> 16);
}

// global -> LDS direct copy, 16B per lane (CK addrspace-cast pattern)
__device__ __forceinline__ void gload_lds16(const void* g, void* l) {
  __builtin_amdgcn_global_load_lds(
      reinterpret_cast<const __attribute__((address_space(1))) void*>(
          reinterpret_cast<uintptr_t>(g)),
      reinterpret_cast<__attribute__((address_space(3))) void*>(
          reinterpret_cast<uintptr_t>(l)),
      16, 0, 0);
}

// ---------------- fused prep: x fp32->bf16 (blocks 0..2047) + weight pack (2048..4095) ----
// pack: Wpt[k][c][d] bf16, c = (h>>4)*32 + u*16 + (h&15), u=0:V 1:U
__global__ void prep_kernel(const float* __restrict__ x,
                            unsigned short* __restrict__ xb,
                            const float* __restrict__ Vw,
                            const float* __restrict__ Uw,
                            unsigned short* __restrict__ Wpt) {
  __shared__ unsigned short T[128][68];
  const int bid = blockIdx.x;
  const int t = threadIdx.x;
  if (bid < 2048) {
    const int total4 = (N_PATCH * DIM) / 4;
    for (int i = bid * 256 + t; i < total4; i += 2048 * 256) {
      float4 v = ((const float4*)x)[i];
      ushort4 o;
      o.x = f2bf(v.x); o.y = f2bf(v.y); o.z = f2bf(v.z); o.w = f2bf(v.w);
      ((ushort4*)xb)[i] = o;
    }
    return;
  }
  const int idx = bid - 2048;
  const int hc = idx & 7;          // h chunk of 64
  const int dc = (idx >> 3) & 15;  // d chunk of 64
  const int k  = idx >> 7;         // head
  const int d0 = dc * 64, h0 = hc * 64;
  const size_t base = (size_t)k * DIM * HID;
  for (int u = 0; u < 2; ++u) {
    const float* W = u ? Uw : Vw;
    #pragma unroll
    for (int i = 0; i < 16; ++i) {
      int ii = i * 256 + t;
      int dd = ii >> 6, hh = ii & 63;
      float v = W[base + (size_t)(d0 + dd) * HID + h0 + hh];
      int cl = ((hh >> 4) << 5) + (u << 4) + (hh & 15);
      T[cl][dd] = f2bf(v);
    }
  }
  __syncthreads();
  const size_t obase = ((size_t)k * 1024 + hc * 128) * DIM + d0;
  #pragma unroll
  for (int i = 0; i < 8; ++i) {
    int ii = i * 1024 + t * 4;
    int cl = ii >> 6, dd = ii & 63;
    ushort4 o;
    o.x = T[cl][dd]; o.y = T[cl][dd + 1]; o.z = T[cl][dd + 2]; o.w = T[cl][dd + 3];
    *(ushort4*)&Wpt[obase + (size_t)cl * DIM + dd] = o;
  }
}

// ---------------- main GEMM + gated epilogue -> score partials ----------------
// 128x256 block tile, BK=64, 8 waves (2M x 4N, 64x64 out/wave), register
// ping-pong: MFMA(tile u, regs from iter u-1) overlaps ds_read(tile u+1) and
// staging(tile u+2) -> DS and MFMA pipes run concurrently. 3-bit XOR swizzle.
__global__ __launch_bounds__(512, 2) void gemm_scores_kernel(
    const unsigned short* __restrict__ xb,
    const unsigned short* __restrict__ Wpt,
    const float* __restrict__ Vb, const float* __restrict__ Ub,
    const float* __restrict__ ww, float* __restrict__ part) {
  __shared__ unsigned short As[2][8192];    // 2 x 16 KB (128 rows x 64 k)
  __shared__ unsigned short Bs[2][16384];   // 2 x 32 KB (256 rows x 64 k)
  const int bid = blockIdx.x;
  // L2-aware bijective map: XCD rectangle 16mt x 32ct; window 8mt x 4ct (4MB)
  const int x8 = bid & 7;
  const int s  = (bid >> 3) & 31;
  const int w  = bid >> 8;                  // 0..15
  const int mt = (x8 & 3) * 16 + (w & 1) * 8 + (s >> 2);     // 0..63 (128-row tiles)
  const int ct = (x8 >> 2) * 32 + (w >> 1) * 4 + (s & 3);    // 0..63 (256-col tiles)
  const int kh = ct >> 2, cb = ct & 3;
  const int tid = threadIdx.x;
  const int wv = tid >> 6, lane = tid & 63;
  const int wr = wv >> 2, wc = wv & 3;      // 2 x 4 wave grid, 64x64 per wave
  const int l15 = lane & 15, l4 = lane >> 4;

  const unsigned short* Ab = xb + (size_t)mt * 128 * DIM;
  const unsigned short* Bb = Wpt + (size_t)ct * 256 * DIM;

  const f32x4 vzero = {0.f, 0.f, 0.f, 0.f};
  f32x4 acc[4][4];   // 64 AGPR
  #pragma unroll
  for (int i = 0; i < 4; ++i)
    #pragma unroll
    for (int j = 0; j < 4; ++j) acc[i][j] = vzero;

  // ---- staging: tile t -> buf t&1; A 2 passes + B 4 passes, 16B/thread each,
  //      linear LDS dest, inverse-swizzled global source (elem ^= ((r>>1)&7)<<3)
  auto stageAll = [&](int t) {
    const int buf = t & 1, db = t << 6;
    const int rr = tid >> 3;
    const int kv = (tid & 7) * 8;
    #pragma unroll
    for (int p = 0; p < 2; ++p) {
      const int r = p * 64 + rr;
      const int ksrc = kv ^ (((r >> 1) & 7) << 3);
      gload_lds16(Ab + (size_t)r * DIM + db + ksrc,
                  (char*)&As[buf][0] + p * 8192 + wv * 1024);
    }
    #pragma unroll
    for (int p = 0; p < 4; ++p) {
      const int r = p * 64 + rr;
      const int ksrc = kv ^ (((r >> 1) & 7) << 3);
      gload_lds16(Bb + (size_t)r * DIM + db + ksrc,
                  (char*)&Bs[buf][0] + p * 8192 + wv * 1024);
    }
  };

  // ---- hoisted swizzled read addresses (per-lane constants) ----
  const int swz = ((l15 >> 1) & 7) << 4;
  const int kb0 = (l4 * 16) ^ swz;
  const int aB0 = wr * 8192 + l15 * 128 + kb0;   // frag f: +f*2048; ks=1: ^64
  const int bB0 = wc * 8192 + l15 * 128 + kb0;   // frag nf: +nf*2048

  short8 aX[8], bX[8], aY[8], bY[8];
  auto rdA = [&](int buf, short8* dst) {     // 8 x ds_read_b128
    const char* base = (const char*)&As[buf][0];
    #pragma unroll
    for (int f = 0; f < 4; ++f) {
      dst[f * 2 + 0] = *(const short8*)(base + (aB0 + f * 2048));
      dst[f * 2 + 1] = *(const short8*)(base + ((aB0 + f * 2048) ^ 64));
    }
  };
  auto rdB = [&](int buf, short8* dst) {     // 8 x ds_read_b128
    const char* base = (const char*)&Bs[buf][0];
    #pragma unroll
    for (int nf = 0; nf < 4; ++nf) {
      dst[nf * 2 + 0] = *(const short8*)(base + (bB0 + nf * 2048));
      dst[nf * 2 + 1] = *(const short8*)(base + ((bB0 + nf * 2048) ^ 64));
    }
  };
  auto mfmaAll = [&](const short8* A_, const short8* B_) {   // 32 MFMA
    __builtin_amdgcn_s_setprio(1);
    #pragma unroll
    for (int f = 0; f < 4; ++f)
      #pragma unroll
      for (int nf = 0; nf < 4; ++nf)
        #pragma unroll
        for (int ks = 0; ks < 2; ++ks)
          acc[f][nf] = __builtin_amdgcn_mfma_f32_16x16x32_bf16(
              A_[f * 2 + ks], B_[nf * 2 + ks], acc[f][nf], 0, 0, 0);
    __builtin_amdgcn_s_setprio(0);
  };

  // ---- prologue: stage tiles 0,1; read tile-0 frags; extra barrier so the
  //      buf0 reads are barrier-separated from iter-0's stage(2 -> buf0) ----
  stageAll(0); stageAll(1);
  __syncthreads();
  rdA(0, aX); rdB(0, bX);
  __syncthreads();

  // ---- main loop (pairs): MFMA(cur) || ds_read(next) || stage(next+1) ----
  for (int u = 0; u < 14; u += 2) {
    // iter u: cur = X (tile u), next = Y (tile u+1 from buf1)
    rdA(1, aY); rdB(1, bY);
    stageAll(u + 2);                 // -> buf0 (reads of buf0 were iter u-1)
    mfmaAll(aX, bX);
    __syncthreads();
    // iter u+1: cur = Y, next = X (tile u+2 from buf0)
    rdA(0, aX); rdB(0, bX);
    stageAll(u + 3);                 // -> buf1
    mfmaAll(aY, bY);
    __syncthreads();
  }
  // u=14: read tile 15 (buf1), no staging
  rdA(1, aY); rdB(1, bY);
  mfmaAll(aX, bX);
  // u=15: compiler inserts lgkm waits for aY/bY
  mfmaAll(aY, bY);

  // ---- gated epilogue: tanh(AV+Vb)*sigmoid(AU+Ub)*ww, reduce 16 lanes ----
  float partial[4][4];
  #pragma unroll
  for (int f = 0; f < 4; ++f)
    #pragma unroll
    for (int r = 0; r < 4; ++r) partial[f][r] = 0.f;

  #pragma unroll
  for (int p = 0; p < 2; ++p) {
    const int hl = (cb * 8 + wc * 2 + p) * 16 + l15;   // head-local h
    const float vb  = Vb[kh * HID + hl];
    const float ub  = Ub[kh * HID + hl];
    const float wwv = ww[kh * HID + hl];
    #pragma unroll
    for (int f = 0; f < 4; ++f)
      #pragma unroll
      for (int r = 0; r < 4; ++r) {
        const float xv = acc[f][2 * p][r] + vb;
        const float e2 = __expf(2.f * xv);
        const float av = 1.f - 2.f / (e2 + 1.f);       // tanh
        const float xu = acc[f][2 * p + 1][r] + ub;
        const float au = 1.f / (1.f + __expf(-xu));    // sigmoid
        partial[f][r] += av * au * wwv;
      }
  }
  #pragma unroll
  for (int s2 = 1; s2 < 16; s2 <<= 1)
    #pragma unroll
    for (int f = 0; f < 4; ++f)
      #pragma unroll
      for (int r = 0; r < 4; ++r)
        partial[f][r] += __shfl_xor(partial[f][r], s2, 64);

  if (l15 == 0) {
    const int j = cb * 4 + wc;   // 0..15 partial slot
    float* dst = part + ((size_t)j * NHEAD + kh) * N_PATCH;
    const int rbase = mt * 128 + wr * 64 + l4 * 4;
    #pragma unroll
    for (int f = 0; f < 4; ++f)
      #pragma unroll
      for (int r = 0; r < 4; ++r)
        dst[rbase + f * 16 + r] = partial[f][r];
  }
}

// ---------------- scores + per-chunk softmax partials (128 blocks) ----------------
__global__ void scores_part_kernel(const float* __restrict__ part,
                                   float* __restrict__ scores,
                                   float* __restrict__ spart) {
  const int k = blockIdx.x >> 3, c = blockIdx.x & 7;
  const int t = threadIdx.x;   // 256
  __shared__ float shm[4], shs[4];
  float v[4];
  float mx = -1e30f;
  #pragma unroll
  for (int i = 0; i < 4; ++i) {
    const int n = c * 1024 + i * 256 + t;
    float s = 0.f;
    #pragma unroll
    for (int j = 0; j < 16; ++j) s += part[((size_t)j * NHEAD + k) * N_PATCH + n];
    v[i] = s;
    scores[(size_t)k * N_PATCH + n] = s;
    mx = fmaxf(mx, s);
  }
  #pragma unroll
  for (int sft = 32; sft; sft >>= 1) mx = fmaxf(mx, __shfl_xor(mx, sft, 64));
  const int wv = t >> 6;
  if ((t & 63) == 0) shm[wv] = mx;
  __syncthreads();
  mx = fmaxf(fmaxf(shm[0], shm[1]), fmaxf(shm[2], shm[3]));
  float sum = 0.f;
  #pragma unroll
  for (int i = 0; i < 4; ++i) sum += __expf(v[i] - mx);
  #pragma unroll
  for (int sft = 32; sft; sft >>= 1) sum += __shfl_xor(sum, sft, 64);
  if ((t & 63) == 0) shs[wv] = sum;
  __syncthreads();
  if (t == 0) {
    spart[(k * 8 + c) * 2]     = mx;
    spart[(k * 8 + c) * 2 + 1] = shs[0] + shs[1] + shs[2] + shs[3];
  }
}

// ---------------- fused: head stats from spart; w[n]=sum_k softmax; partial col-sums (bf16 x) ----
__global__ void weighted_part_kernel(const unsigned short* __restrict__ xb,
                                     const float* __restrict__ scores,
                                     const float* __restrict__ spart,
                                     float* __restrict__ wp1,
                                     float* __restrict__ wp2) {
  __shared__ float wrow[128];
  __shared__ float sm[16], srz[16];
  const int d = blockIdx.x * 256 + threadIdx.x;  // grid.x = 4
  const int nc = blockIdx.y;                     // 64 chunks of 128 rows
  if (threadIdx.x < 16) {
    const int k = threadIdx.x;
    float m = -1e30f;
    #pragma unroll
    for (int c = 0; c < 8; ++c) m = fmaxf(m, spart[(k * 8 + c) * 2]);
    float S = 0.f;
    #pragma unroll
    for (int c = 0; c < 8; ++c)
      S += spart[(k * 8 + c) * 2 + 1] * __expf(spart[(k * 8 + c) * 2] - m);
    sm[k] = m; srz[k] = 1.f / S;
  }
  __syncthreads();
  if (threadIdx.x < 128) {
    const int n = nc * 128 + threadIdx.x;
    float s = 0.f;
    #pragma unroll
    for (int k = 0; k < NHEAD; ++k)
      s += __expf(scores[(size_t)k * N_PATCH + n] - sm[k]) * srz[k];
    wrow[threadIdx.x] = s;
  }
  __syncthreads();
  float a1 = 0.f, a2 = 0.f;
  for (int i = 0; i < 128; ++i) {
    unsigned uv = xb[(size_t)(nc * 128 + i) * DIM + d];
    float xv = __uint_as_float(uv << 16);
    a1 += wrow[i] * xv;
    a2 += xv;
  }
  wp1[nc * DIM + d] = a1;
  wp2[nc * DIM + d] = a2;
}

__global__ void reduce_vec_kernel(const float* __restrict__ wp1,
                                  const float* __restrict__ wp2,
                                  float* __restrict__ y1,
                                  float* __restrict__ mvec) {
  int d = blockIdx.x * 256 + threadIdx.x;
  float s1 = 0.f, s2 = 0.f;
  #pragma unroll
  for (int i = 0; i < 64; ++i) {
    s1 += wp1[i * DIM + d];
    s2 += wp2[i * DIM + d];
  }
  y1[d] = s1;
  mvec[d] = s2 * (1.f / (float)N_PATCH);
}

// ---------------- one-dispatch GEMV: in-block split-K (4 kc x 64 j), LDS reduce ----
__global__ void gemv_fused_kernel(const float* __restrict__ in,
                                  const float* __restrict__ W,
                                  const float* __restrict__ bias,
                                  const float* __restrict__ extra, float scale,
                                  int do_relu, float* __restrict__ out,
                                  int In, int Out) {
  __shared__ float red[4][64];
  const int jl = threadIdx.x & 63, kc = threadIdx.x >> 6;
  const int j = blockIdx.x * 64 + jl;
  const int chunk = In >> 2;
  const float* Wp = W + (size_t)(kc * chunk) * Out + j;
  const float* ip = in + kc * chunk;
  float acc = 0.f;
  #pragma unroll 4
  for (int d = 0; d < chunk; ++d) acc += ip[d] * Wp[(size_t)d * Out];
  if (kc) red[kc][jl] = acc;
  __syncthreads();
  if (kc == 0) {
    float v = bias[j] + acc + red[1][jl] + red[2][jl] + red[3][jl];
    if (extra) v += extra[j];
    v *= scale;
    if (do_relu) v = fmaxf(v, 0.f);
    out[j] = v;
  }
}

// ---------------- fused: c3 = relu(c2@cW3+cb3); logits = c3@cW4+cb4; softmax ----
__global__ void c3_final_kernel(const float* __restrict__ c2,
                                const float* __restrict__ W3,
                                const float* __restrict__ b3,
                                const float* __restrict__ W4,
                                const float* __restrict__ b4,
                                float* __restrict__ out) {
  __shared__ float c3s[256];
  __shared__ float logits[9];
  const int t = threadIdx.x;   // 256
  float acc = b3[t];
  #pragma unroll 4
  for (int d = 0; d < 512; ++d) acc += c2[d] * W3[(size_t)d * 256 + t];
  c3s[t] = fmaxf(acc, 0.f);
  __syncthreads();
  if (t < 9) {
    float l = b4[t];
    for (int d = 0; d < 256; ++d) l += c3s[d] * W4[d * 9 + t];
    logits[t] = l;
  }
  __syncthreads();
  if (t == 0) {
    float mx = logits[0];
    for (int j = 1; j < 9; ++j) mx = fmaxf(mx, logits[j]);
    float e[9], s = 0.f;
    for (int j = 0; j < 9; ++j) { e[j] = expf(logits[j] - mx); s += e[j]; }
    for (int j = 0; j < 9; ++j) out[j] = e[j] / s;
  }
}

extern "C" void kernel_launch(void* const* d_in, const int* in_sizes, int n_in,
                              void* d_out, int out_size, void* d_ws, size_t ws_size,
                              hipStream_t stream) {
  (void)in_sizes; (void)n_in; (void)out_size; (void)ws_size;
  const float* x   = (const float*)d_in[0];
  const float* Vw  = (const float*)d_in[1];
  const float* Vb  = (const float*)d_in[2];
  const float* Uw  = (const float*)d_in[3];
  const float* Ub  = (const float*)d_in[4];
  const float* ww  = (const float*)d_in[5];
  // d_in[6] = wb: constant per head -> softmax invariant -> unused
  const float* pW1 = (const float*)d_in[7];
  const float* pb1 = (const float*)d_in[8];
  const float* pW2 = (const float*)d_in[9];
  const float* pb2 = (const float*)d_in[10];
  const float* cW1 = (const float*)d_in[11];
  const float* cb1 = (const float*)d_in[12];
  const float* cW2 = (const float*)d_in[13];
  const float* cb2 = (const float*)d_in[14];
  const float* cW3 = (const float*)d_in[15];
  const float* cb3 = (const float*)d_in[16];
  const float* cW4 = (const float*)d_in[17];
  const float* cb4 = (const float*)d_in[18];
  float* out = (float*)d_out;

  char* ws = (char*)d_ws;
  size_t o = 0;
  auto alloc = [&](size_t bytes) -> char* {
    char* p = ws + o;
    o += (bytes + 255) & ~(size_t)255;
    return p;
  };
  unsigned short* xb  = (unsigned short*)alloc((size_t)N_PATCH * DIM * 2);      // 16 MB
  unsigned short* Wpt = (unsigned short*)alloc((size_t)NHEAD * 1024 * DIM * 2); // 32 MB
  float* part   = (float*)alloc((size_t)16 * NHEAD * N_PATCH * 4);              // 8 MB
  float* scores = (float*)alloc((size_t)NHEAD * N_PATCH * 4);
  float* spart  = (float*)alloc(NHEAD * 8 * 2 * 4);
  float* wp1    = (float*)alloc(64 * DIM * 4);
  float* wp2    = (float*)alloc(64 * DIM * 4);
  float* y1     = (float*)alloc(DIM * 4);
  float* mvec   = (float*)alloc(DIM * 4);
  float* h1     = (float*)alloc(HID * 4);
  float* aggr   = (float*)alloc(DIM * 4);
  float* c1     = (float*)alloc(1024 * 4);
  float* c2     = (float*)alloc(512 * 4);

  prep_kernel<<<4096, 256, 0, stream>>>(x, xb, Vw, Uw, Wpt);
  gemm_scores_kernel<<<4096, 512, 0, stream>>>(xb, Wpt, Vb, Ub, ww, part);
  scores_part_kernel<<<128, 256, 0, stream>>>(part, scores, spart);
  weighted_part_kernel<<<dim3(4, 64), 256, 0, stream>>>(xb, scores, spart, wp1, wp2);
  reduce_vec_kernel<<<4, 256, 0, stream>>>(wp1, wp2, y1, mvec);
  gemv_fused_kernel<<<8, 256, 0, stream>>>(mvec, pW1, pb1, nullptr, 1.f, 1, h1, DIM, HID);
  gemv_fused_kernel<<<16, 256, 0, stream>>>(h1, pW2, pb2, y1, 1.f / 17.f, 0, aggr, HID, DIM);
  gemv_fused_kernel<<<16, 256, 0, stream>>>(aggr, cW1, cb1, nullptr, 1.f, 1, c1, 1024, 1024);
  gemv_fused_kernel<<<8, 256, 0, stream>>>(c1, cW2, cb2, nullptr, 1.f, 1, c2, 1024, 512);
  c3_final_kernel<<<1, 256, 0, stream>>>(c2, cW3, cb3, cW4, cb4, out);
}

// Round 12
// 465.580 us; speedup vs baseline: 1.0659x; 1.0659x over previous
//
#include <hip/hip_runtime.h>
#include <stdint.h>

#define N_PATCH 8192
#define DIM     1024
#define HID     512
#define NHEAD   16

using i32x4 = __attribute__((ext_vector_type(4))) int;

__device__ __forceinline__ void gload_lds16(const void* g, void* l) {
  __builtin_amdgcn_global_load_lds(
      reinterpret_cast<const __attribute__((address_space(1))) void*>(
          reinterpret_cast<uintptr_t>(g)),
      reinterpret_cast<__attribute__((address_space(3))) void*>(
          reinterpret_cast<uintptr_t>(l)),
      16, 0, 0);
}

__device__ __forceinline__ int q8(float v, float rs) {
  int q = (int)rintf(v * rs);
  return q > 127 ? 127 : (q < -127 ? -127 : q);
}

// ---------------- prep1: quantize x per-row (bid<2048) + W column amax (bid>=2048) ----
__global__ void prep1_kernel(const float* __restrict__ x,
                             signed char* __restrict__ xq, float* __restrict__ sx,
                             const float* __restrict__ Vw, const float* __restrict__ Uw,
                             float* __restrict__ swp, float* __restrict__ rswp) {
  __shared__ float red[2][128];
  const int bid = blockIdx.x;
  const int t = threadIdx.x;
  if (bid < 2048) {            // ---- x: one wave per row, 4 rows/block ----
    const int row = bid * 4 + (t >> 6);
    const int lane = t & 63;
    const float* xr = x + (size_t)row * DIM;
    float4 v[4];
    float am = 0.f;
    #pragma unroll
    for (int j = 0; j < 4; ++j) {
      v[j] = *(const float4*)&xr[j * 256 + lane * 4];
      am = fmaxf(am, fmaxf(fmaxf(fabsf(v[j].x), fabsf(v[j].y)),
                           fmaxf(fabsf(v[j].z), fabsf(v[j].w))));
    }
    #pragma unroll
    for (int s = 32; s; s >>= 1) am = fmaxf(am, __shfl_xor(am, s, 64));
    const float rs = (am > 0.f) ? 127.f / am : 0.f;
    #pragma unroll
    for (int j = 0; j < 4; ++j) {
      int b = (q8(v[j].x, rs) & 255) | ((q8(v[j].y, rs) & 255) << 8) |
              ((q8(v[j].z, rs) & 255) << 16) | ((q8(v[j].w, rs) & 255) << 24);
      ((int*)xq)[row * 256 + j * 64 + lane] = b;
    }
    if (lane == 0) sx[row] = am / 127.f;
    return;
  }
  // ---- W column amax: 128 blocks = u(2) x k(16) x hc2(4) ----
  const int b2 = bid - 2048;
  const int u = b2 >> 6, rem = b2 & 63;
  const int k = rem >> 2, hc2 = rem & 3;
  const float* W = u ? Uw : Vw;
  const size_t base = (size_t)k * DIM * HID + hc2 * 128;
  const int hh = t & 127, dh = t >> 7;
  float am = 0.f;
  for (int i = 0; i < 512; ++i)
    am = fmaxf(am, fabsf(W[base + (size_t)(dh * 512 + i) * HID + hh]));
  red[dh][hh] = am;
  __syncthreads();
  if (t < 128) {
    float m = fmaxf(red[0][t], red[1][t]);
    const int h = hc2 * 128 + t;
    const int c = (h >> 4) * 32 + u * 16 + (h & 15);   // within-k packed col
    swp[k * 1024 + c]  = m / 127.f;
    rswp[k * 1024 + c] = (m > 0.f) ? 127.f / m : 0.f;
  }
}

// ---------------- prep2: pack W -> Wq[col][d] int8 (512 blocks: k16 x hc8 x dc4) ----
__global__ void pack_wq_kernel(const float* __restrict__ Vw,
                               const float* __restrict__ Uw,
                               const float* __restrict__ rswp,
                               signed char* __restrict__ Wq) {
  __shared__ __align__(16) signed char T[128][256];   // 32 KB
  const int bid = blockIdx.x;
  const int k = bid >> 5, hc = (bid >> 2) & 7, dc = bid & 3;
  const int t = threadIdx.x;
  const int hh = t & 63, dq = t >> 6;
  #pragma unroll
  for (int u = 0; u < 2; ++u) {
    const int h = hc * 64 + hh;
    const int c = (h >> 4) * 32 + u * 16 + (h & 15);
    const int cl = c - hc * 128;
    const float rs = rswp[k * 1024 + c];
    const float* W = u ? Uw : Vw;
    const size_t base = (size_t)k * DIM * HID + h;
    for (int i = 0; i < 64; ++i) {
      const int d = dc * 256 + dq * 64 + i;
      T[cl][dq * 64 + i] = (signed char)q8(W[base + (size_t)d * HID], rs);
    }
  }
  __syncthreads();
  #pragma unroll
  for (int j = 0; j < 8; ++j) {
    const int idx = j * 256 + t;
    const int cl2 = idx >> 4, ch = idx & 15;
    i32x4 val = *(const i32x4*)&T[cl2][ch * 16];
    const size_t col = (size_t)(k * 4 + (hc >> 1)) * 256 + (hc & 1) * 128 + cl2;
    *(i32x4*)&Wq[col * 1024 + dc * 256 + ch * 16] = val;
  }
}

// ---------------- main GEMM (int8) + gated epilogue -> score partials ----------------
// 256x256 tile, BK=64 (64B rows), 8 waves (2M x 4N), mfma_i32_16x16x64_i8,
// 2-bit XOR swizzle (2 lanes/bank = free), one barrier/K-tile (wave-skew overlap),
// L2-aware 2D block map. Dequant in epilogue: sx[row] * swp[col] * acc.
__global__ __launch_bounds__(512, 1) void gemm_scores_kernel(
    const signed char* __restrict__ xq, const signed char* __restrict__ Wq,
    const float* __restrict__ sx, const float* __restrict__ swp,
    const float* __restrict__ Vb, const float* __restrict__ Ub,
    const float* __restrict__ ww, float* __restrict__ part) {
  __shared__ __align__(16) signed char As[2][16384];   // 2 x 16 KB
  __shared__ __align__(16) signed char Bs[2][16384];
  const int bid = blockIdx.x;
  const int x8 = bid & 7;
  const int s  = (bid >> 3) & 31;
  const int w  = bid >> 8;
  const int mt = (x8 & 1) * 16 + (w & 1) * 8 + (s >> 2);   // 0..31
  const int ct = (x8 >> 1) * 16 + (w >> 1) * 4 + (s & 3);  // 0..63
  const int kh = ct >> 2, cb = ct & 3;
  const int tid = threadIdx.x;
  const int wv = tid >> 6, lane = tid & 63;
  const int wr = wv >> 2, wc = wv & 3;
  const int l15 = lane & 15, l4 = lane >> 4;

  const signed char* Ab = xq + (size_t)mt * 256 * DIM;
  const signed char* Bb = Wq + (size_t)ct * 256 * DIM;

  i32x4 acc[8][4];
  #pragma unroll
  for (int i = 0; i < 8; ++i)
    #pragma unroll
    for (int j = 0; j < 4; ++j) acc[i][j] = (i32x4){0, 0, 0, 0};

  // stage: tile t (64 int8 per row) -> buf t&1; A: 2 passes, B: 2 passes
  auto stageA = [&](int t) {
    const int buf = t & 1, db = t << 6;
    #pragma unroll
    for (int p = 0; p < 2; ++p) {
      const int r = p * 128 + (tid >> 2);
      const int ksrc = ((tid & 3) * 16) ^ (((r >> 1) & 3) << 4);
      gload_lds16(Ab + (size_t)r * DIM + db + ksrc,
                  (char*)&As[buf][0] + p * 8192 + wv * 1024);
    }
  };
  auto stageB = [&](int t) {
    const int buf = t & 1, db = t << 6;
    #pragma unroll
    for (int p = 0; p < 2; ++p) {
      const int r = p * 128 + (tid >> 2);
      const int ksrc = ((tid & 3) * 16) ^ (((r >> 1) & 3) << 4);
      gload_lds16(Bb + (size_t)r * DIM + db + ksrc,
                  (char*)&Bs[buf][0] + p * 8192 + wv * 1024);
    }
  };

  // hoisted read addresses: swz depends only on l15 (row = 16f + l15 pattern)
  const int swz = ((l15 >> 1) & 3) << 4;
  const int kb0 = (l4 * 16) ^ swz;
  const int aB0 = wr * 8192 + l15 * 64 + kb0;   // frag f: +f*1024
  const int bB0 = wc * 4096 + l15 * 64 + kb0;   // frag nf: +nf*1024

  i32x4 a[8], b[4];

  stageA(0); stageB(0); stageA(1); stageB(1);
  __syncthreads();

  for (int u = 0; u < 16; ++u) {
    const int buf = u & 1;
    const char* Abase = (const char*)&As[buf][0];
    const char* Bbase = (const char*)&Bs[buf][0];
    #pragma unroll
    for (int f = 0; f < 8; ++f) a[f] = *(const i32x4*)(Abase + aB0 + f * 1024);
    #pragma unroll
    for (int nf = 0; nf < 4; ++nf) b[nf] = *(const i32x4*)(Bbase + bB0 + nf * 1024);
    if (u < 15) { stageA(u + 1); stageB(u + 1); }
    __builtin_amdgcn_s_setprio(1);
    #pragma unroll
    for (int f = 0; f < 8; ++f)
      #pragma unroll
      for (int nf = 0; nf < 4; ++nf)
        acc[f][nf] = __builtin_amdgcn_mfma_i32_16x16x64_i8(a[f], b[nf], acc[f][nf], 0, 0, 0);
    __builtin_amdgcn_s_setprio(0);
    __syncthreads();
  }

  // ---- gated epilogue with dequant ----
  float partial[8][4];
  #pragma unroll
  for (int f = 0; f < 8; ++f)
    #pragma unroll
    for (int r = 0; r < 4; ++r) partial[f][r] = 0.f;

  float vb[2], ub[2], wwv[2], swv[2], swu[2];
  #pragma unroll
  for (int p = 0; p < 2; ++p) {
    const int hl = (cb * 8 + wc * 2 + p) * 16 + l15;
    vb[p]  = Vb[kh * HID + hl];
    ub[p]  = Ub[kh * HID + hl];
    wwv[p] = ww[kh * HID + hl];
    swv[p] = swp[ct * 256 + wc * 64 + (2 * p) * 16 + l15];
    swu[p] = swp[ct * 256 + wc * 64 + (2 * p + 1) * 16 + l15];
  }
  const int rbase = mt * 256 + wr * 128 + l4 * 4;
  #pragma unroll
  for (int f = 0; f < 8; ++f) {
    const float4 sx4 = *(const float4*)&sx[rbase + f * 16];
    const float sxr[4] = {sx4.x, sx4.y, sx4.z, sx4.w};
    #pragma unroll
    for (int p = 0; p < 2; ++p)
      #pragma unroll
      for (int r = 0; r < 4; ++r) {
        const float scv = (float)acc[f][2 * p][r] * (sxr[r] * swv[p]) + vb[p];
        const float scu = (float)acc[f][2 * p + 1][r] * (sxr[r] * swu[p]) + ub[p];
        const float e2 = __expf(2.f * scv);
        const float av = 1.f - 2.f / (e2 + 1.f);          // tanh
        const float au = 1.f / (1.f + __expf(-scu));      // sigmoid
        partial[f][r] += av * au * wwv[p];
      }
  }
  #pragma unroll
  for (int s2 = 1; s2 < 16; s2 <<= 1)
    #pragma unroll
    for (int f = 0; f < 8; ++f)
      #pragma unroll
      for (int r = 0; r < 4; ++r)
        partial[f][r] += __shfl_xor(partial[f][r], s2, 64);

  if (l15 == 0) {
    const int j = cb * 4 + wc;
    float* dst = part + ((size_t)j * NHEAD + kh) * N_PATCH;
    #pragma unroll
    for (int f = 0; f < 8; ++f)
      #pragma unroll
      for (int r = 0; r < 4; ++r)
        dst[rbase + f * 16 + r] = partial[f][r];
  }
}

// ---------------- scores + per-chunk softmax partials (128 blocks) ----------------
__global__ void scores_part_kernel(const float* __restrict__ part,
                                   float* __restrict__ scores,
                                   float* __restrict__ spart) {
  const int k = blockIdx.x >> 3, c = blockIdx.x & 7;
  const int t = threadIdx.x;
  __shared__ float shm[4], shs[4];
  float v[4];
  float mx = -1e30f;
  #pragma unroll
  for (int i = 0; i < 4; ++i) {
    const int n = c * 1024 + i * 256 + t;
    float s = 0.f;
    #pragma unroll
    for (int j = 0; j < 16; ++j) s += part[((size_t)j * NHEAD + k) * N_PATCH + n];
    v[i] = s;
    scores[(size_t)k * N_PATCH + n] = s;
    mx = fmaxf(mx, s);
  }
  #pragma unroll
  for (int sft = 32; sft; sft >>= 1) mx = fmaxf(mx, __shfl_xor(mx, sft, 64));
  const int wv = t >> 6;
  if ((t & 63) == 0) shm[wv] = mx;
  __syncthreads();
  mx = fmaxf(fmaxf(shm[0], shm[1]), fmaxf(shm[2], shm[3]));
  float sum = 0.f;
  #pragma unroll
  for (int i = 0; i < 4; ++i) sum += __expf(v[i] - mx);
  #pragma unroll
  for (int sft = 32; sft; sft >>= 1) sum += __shfl_xor(sum, sft, 64);
  if ((t & 63) == 0) shs[wv] = sum;
  __syncthreads();
  if (t == 0) {
    spart[(k * 8 + c) * 2]     = mx;
    spart[(k * 8 + c) * 2 + 1] = shs[0] + shs[1] + shs[2] + shs[3];
  }
}

// ---------------- fused: stats; w[n]=sum_k softmax; partial col-sums (fp32 x) ----
__global__ void weighted_part_kernel(const float* __restrict__ x,
                                     const float* __restrict__ scores,
                                     const float* __restrict__ spart,
                                     float* __restrict__ wp1,
                                     float* __restrict__ wp2) {
  __shared__ float wrow[128];
  __shared__ float sm[16], srz[16];
  const int d = blockIdx.x * 256 + threadIdx.x;
  const int nc = blockIdx.y;
  if (threadIdx.x < 16) {
    const int k = threadIdx.x;
    float m = -1e30f;
    #pragma unroll
    for (int c = 0; c < 8; ++c) m = fmaxf(m, spart[(k * 8 + c) * 2]);
    float S = 0.f;
    #pragma unroll
    for (int c = 0; c < 8; ++c)
      S += spart[(k * 8 + c) * 2 + 1] * __expf(spart[(k * 8 + c) * 2] - m);
    sm[k] = m; srz[k] = 1.f / S;
  }
  __syncthreads();
  if (threadIdx.x < 128) {
    const int n = nc * 128 + threadIdx.x;
    float s = 0.f;
    #pragma unroll
    for (int k = 0; k < NHEAD; ++k)
      s += __expf(scores[(size_t)k * N_PATCH + n] - sm[k]) * srz[k];
    wrow[threadIdx.x] = s;
  }
  __syncthreads();
  float a1 = 0.f, a2 = 0.f;
  for (int i = 0; i < 128; ++i) {
    float xv = x[(size_t)(nc * 128 + i) * DIM + d];
    a1 += wrow[i] * xv;
    a2 += xv;
  }
  wp1[nc * DIM + d] = a1;
  wp2[nc * DIM + d] = a2;
}

__global__ void reduce_vec_kernel(const float* __restrict__ wp1,
                                  const float* __restrict__ wp2,
                                  float* __restrict__ y1,
                                  float* __restrict__ mvec) {
  int d = blockIdx.x * 256 + threadIdx.x;
  float s1 = 0.f, s2 = 0.f;
  #pragma unroll
  for (int i = 0; i < 64; ++i) {
    s1 += wp1[i * DIM + d];
    s2 += wp2[i * DIM + d];
  }
  y1[d] = s1;
  mvec[d] = s2 * (1.f / (float)N_PATCH);
}

// ---------------- one-dispatch GEMV: in-block split-K (4 kc x 64 j) ----------------
__global__ void gemv_fused_kernel(const float* __restrict__ in,
                                  const float* __restrict__ W,
                                  const float* __restrict__ bias,
                                  const float* __restrict__ extra, float scale,
                                  int do_relu, float* __restrict__ out,
                                  int In, int Out) {
  __shared__ float red[4][64];
  const int jl = threadIdx.x & 63, kc = threadIdx.x >> 6;
  const int j = blockIdx.x * 64 + jl;
  const int chunk = In >> 2;
  const float* Wp = W + (size_t)(kc * chunk) * Out + j;
  const float* ip = in + kc * chunk;
  float acc = 0.f;
  #pragma unroll 4
  for (int d = 0; d < chunk; ++d) acc += ip[d] * Wp[(size_t)d * Out];
  if (kc) red[kc][jl] = acc;
  __syncthreads();
  if (kc == 0) {
    float v = bias[j] + acc + red[1][jl] + red[2][jl] + red[3][jl];
    if (extra) v += extra[j];
    v *= scale;
    if (do_relu) v = fmaxf(v, 0.f);
    out[j] = v;
  }
}

// ---------------- fused: c3 = relu(c2@cW3+cb3); logits; softmax ----------------
__global__ void c3_final_kernel(const float* __restrict__ c2,
                                const float* __restrict__ W3,
                                const float* __restrict__ b3,
                                const float* __restrict__ W4,
                                const float* __restrict__ b4,
                                float* __restrict__ out) {
  __shared__ float c3s[256];
  __shared__ float logits[9];
  const int t = threadIdx.x;
  float acc = b3[t];
  #pragma unroll 4
  for (int d = 0; d < 512; ++d) acc += c2[d] * W3[(size_t)d * 256 + t];
  c3s[t] = fmaxf(acc, 0.f);
  __syncthreads();
  if (t < 9) {
    float l = b4[t];
    for (int d = 0; d < 256; ++d) l += c3s[d] * W4[d * 9 + t];
    logits[t] = l;
  }
  __syncthreads();
  if (t == 0) {
    float mx = logits[0];
    for (int j = 1; j < 9; ++j) mx = fmaxf(mx, logits[j]);
    float e[9], s = 0.f;
    for (int j = 0; j < 9; ++j) { e[j] = expf(logits[j] - mx); s += e[j]; }
    for (int j = 0; j < 9; ++j) out[j] = e[j] / s;
  }
}

extern "C" void kernel_launch(void* const* d_in, const int* in_sizes, int n_in,
                              void* d_out, int out_size, void* d_ws, size_t ws_size,
                              hipStream_t stream) {
  (void)in_sizes; (void)n_in; (void)out_size; (void)ws_size;
  const float* x   = (const float*)d_in[0];
  const float* Vw  = (const float*)d_in[1];
  const float* Vb  = (const float*)d_in[2];
  const float* Uw  = (const float*)d_in[3];
  const float* Ub  = (const float*)d_in[4];
  const float* ww  = (const float*)d_in[5];
  // d_in[6] = wb: constant per head -> softmax invariant -> unused
  const float* pW1 = (const float*)d_in[7];
  const float* pb1 = (const float*)d_in[8];
  const float* pW2 = (const float*)d_in[9];
  const float* pb2 = (const float*)d_in[10];
  const float* cW1 = (const float*)d_in[11];
  const float* cb1 = (const float*)d_in[12];
  const float* cW2 = (const float*)d_in[13];
  const float* cb2 = (const float*)d_in[14];
  const float* cW3 = (const float*)d_in[15];
  const float* cb3 = (const float*)d_in[16];
  const float* cW4 = (const float*)d_in[17];
  const float* cb4 = (const float*)d_in[18];
  float* out = (float*)d_out;

  char* ws = (char*)d_ws;
  size_t o = 0;
  auto alloc = [&](size_t bytes) -> char* {
    char* p = ws + o;
    o += (bytes + 255) & ~(size_t)255;
    return p;
  };
  signed char* xq = (signed char*)alloc((size_t)N_PATCH * DIM);       // 8 MB
  signed char* Wq = (signed char*)alloc((size_t)NHEAD * 1024 * DIM);  // 16 MB
  float* sx    = (float*)alloc(N_PATCH * 4);
  float* swp   = (float*)alloc(NHEAD * 1024 * 4);
  float* rswp  = (float*)alloc(NHEAD * 1024 * 4);
  float* part  = (float*)alloc((size_t)16 * NHEAD * N_PATCH * 4);     // 8 MB
  float* scores= (float*)alloc((size_t)NHEAD * N_PATCH * 4);
  float* spart = (float*)alloc(NHEAD * 8 * 2 * 4);
  float* wp1   = (float*)alloc(64 * DIM * 4);
  float* wp2   = (float*)alloc(64 * DIM * 4);
  float* y1    = (float*)alloc(DIM * 4);
  float* mvec  = (float*)alloc(DIM * 4);
  float* h1    = (float*)alloc(HID * 4);
  float* aggr  = (float*)alloc(DIM * 4);
  float* c1    = (float*)alloc(1024 * 4);
  float* c2    = (float*)alloc(512 * 4);

  prep1_kernel<<<2176, 256, 0, stream>>>(x, xq, sx, Vw, Uw, swp, rswp);
  pack_wq_kernel<<<512, 256, 0, stream>>>(Vw, Uw, rswp, Wq);
  gemm_scores_kernel<<<2048, 512, 0, stream>>>(xq, Wq, sx, swp, Vb, Ub, ww, part);
  scores_part_kernel<<<128, 256, 0, stream>>>(part, scores, spart);
  weighted_part_kernel<<<dim3(4, 64), 256, 0, stream>>>(x, scores, spart, wp1, wp2);
  reduce_vec_kernel<<<4, 256, 0, stream>>>(wp1, wp2, y1, mvec);
  gemv_fused_kernel<<<8, 256, 0, stream>>>(mvec, pW1, pb1, nullptr, 1.f, 1, h1, DIM, HID);
  gemv_fused_kernel<<<16, 256, 0, stream>>>(h1, pW2, pb2, y1, 1.f / 17.f, 0, aggr, HID, DIM);
  gemv_fused_kernel<<<16, 256, 0, stream>>>(aggr, cW1, cb1, nullptr, 1.f, 1, c1, 1024, 1024);
  gemv_fused_kernel<<<8, 256, 0, stream>>>(c1, cW2, cb2, nullptr, 1.f, 1, c2, 1024, 512);
  c3_final_kernel<<<1, 256, 0, stream>>>(c2, cW3, cb3, cW4, cb4, out);
}